// Round 3
// baseline (1128.782 us; speedup 1.0000x reference)
//
#include <hip/hip_runtime.h>
#include <hip/hip_bf16.h>

// WinMSA fused kernel for MI355X (gfx950), v3.
// B=64, WN=64 windows, S=49 (pad 64), C=192, H=6, D=32.
// One block per window, 512 threads (8 waves), TWO barriers total.
// Each wave privately computes Q^T/K^T/V^T for its own (mt, heads) via swapped
// MFMA (A = weight rows from global, B = X^T from shared Xs), bouncing fragment
// transposes through a wave-private LDS scratch (no cross-wave sync needed).
// LDS 73.7KB -> 2 blocks/CU.

typedef __attribute__((ext_vector_type(4))) float f32x4;
typedef __attribute__((ext_vector_type(8))) short bf16x8;
typedef __attribute__((ext_vector_type(4))) unsigned short u16x4;

#define SCALE 0.17677669529663689f  // 32^-0.5
#define XST 200                      // Xs / AO row stride (ushorts)
#define SST 72                       // scratch row stride (ushorts)
#define MFMA(a, b, acc) __builtin_amdgcn_mfma_f32_16x16x32_bf16(a, b, acc, 0, 0, 0)

__device__ __forceinline__ unsigned short f2bf(float f) {
  union { float f; unsigned int u; } v; v.f = f;
  return (unsigned short)((v.u + 0x7FFFu + ((v.u >> 16) & 1u)) >> 16);  // RNE
}

// XOR swizzle on bits 3..4 of the column, keyed by row; preserves 8-ushort
// (16B) blocks so b128/b64 accesses stay contiguous+aligned.
__device__ __forceinline__ int xidx(int row, int col) {
  return row * XST + (col ^ (((row >> 1) & 3) << 3));
}
__device__ __forceinline__ int sidx(int r, int col) {
  return r * SST + (col ^ ((r & 3) << 3));
}

// Pre-kernel: transpose weights to bf16 [out][in] for k-contiguous A/B frags.
__global__ void wprep(const float* __restrict__ Wqkv, const float* __restrict__ Wo,
                      unsigned short* __restrict__ WqkvT, unsigned short* __restrict__ WoT) {
  int i = blockIdx.x * 256 + threadIdx.x;
  if (i < 576 * 192) { int n = i / 192, k = i % 192; WqkvT[i] = f2bf(Wqkv[k * 576 + n]); }
  if (i < 192 * 192) { int n = i / 192, k = i % 192; WoT[i]   = f2bf(Wo[k * 192 + n]); }
}

__device__ __forceinline__ void wr4(unsigned short* sw, int r, int col, f32x4 v) {
  u16x4 p;
  p[0] = f2bf(v[0]); p[1] = f2bf(v[1]); p[2] = f2bf(v[2]); p[3] = f2bf(v[3]);
  *(u16x4*)(sw + sidx(r, col)) = p;  // ds_write_b64
}

__global__ __launch_bounds__(512, 4)
void winmsa(const float* __restrict__ X, const unsigned short* __restrict__ WqkvT,
            const float* __restrict__ bqkv, const unsigned short* __restrict__ WoT,
            const float* __restrict__ bo, const float* __restrict__ btab,
            float* __restrict__ out) {
  __shared__ __align__(16) unsigned short Xs[64 * XST];      // X bf16, swizzled
  __shared__ __align__(16) unsigned short AO[64 * XST];      // attn-out bf16, swizzled
  __shared__ __align__(16) unsigned short scr[8][16 * SST];  // per-wave transpose scratch
  __shared__ float biasF[1014];

  const int tid  = threadIdx.x;
  const int w8   = tid >> 6;
  const int lane = tid & 63;
  const int g    = lane >> 4;   // 0..3
  const int c    = lane & 15;   // 0..15
  const int mt   = w8 & 3;      // query-row tile (16 rows)
  const int hw   = w8 >> 2;     // head half: heads {3hw, 3hw+1, 3hw+2}
  const int wb   = blockIdx.x;

  for (int j = tid; j < 1014; j += 512) biasF[j] = btab[j];
  for (int i = tid; i < 1500; i += 512) ((unsigned int*)(Xs + 49 * XST))[i] = 0u;
  const float* Xg = X + (size_t)wb * 9408;
  for (int j = tid; j < 2352; j += 512) {   // 49*192 floats as float4
    f32x4 x4 = ((const f32x4*)Xg)[j];
    int f = j * 4, row = f / 192, col = f % 192;
    u16x4 p;
    p[0] = f2bf(x4[0]); p[1] = f2bf(x4[1]); p[2] = f2bf(x4[2]); p[3] = f2bf(x4[3]);
    *(u16x4*)(Xs + xidx(row, col)) = p;
  }
  __syncthreads();  // barrier 1: Xs + biasF ready

  // hoisted softmax indexing (same as v2, verified)
  const int q = mt * 16 + c;
  const bool qvalid = q < 49;
  const int qq = qvalid ? q : 48;
  const int qoff6 = ((6 - qq / 7) * 13 + (6 - qq % 7)) * 6;
  int kb6[16];
  #pragma unroll
  for (int i = 0; i < 16; ++i) {
    int k = (i >> 2) * 16 + g * 4 + (i & 3);
    int kk = k < 49 ? k : 48;
    kb6[i] = ((kk / 7) * 13 + (kk % 7)) * 6;
  }

  unsigned short* sw = scr[w8];
  const f32x4 z = {0.f, 0.f, 0.f, 0.f};
  const int cq3 = ((c >> 1) & 3) << 3;  // Xs/AO read swizzle (rows == c mod 16)

  for (int hi = 0; hi < 3; ++hi) {
    const int h = hw * 3 + hi;

    // ---- Q^T = Wq^T @ X^T (d=32 x q=16), A-frags natural WqkvT rows ----
    f32x4 qa0 = z, qa1 = z;
    {
      const unsigned short* wq = WqkvT + (h * 32) * 192 + g * 8;
      #pragma unroll
      for (int ks = 0; ks < 6; ++ks) {
        bf16x8 a0 = *(const bf16x8*)(wq + c * 192 + ks * 32);
        bf16x8 a1 = *(const bf16x8*)(wq + (16 + c) * 192 + ks * 32);
        bf16x8 xb = *(const bf16x8*)(Xs + (mt * 16 + c) * XST + ((ks * 32 + g * 8) ^ cq3));
        qa0 = MFMA(a0, xb, qa0);
        qa1 = MFMA(a1, xb, qa1);
      }
    }
    {
      f32x4 b0 = *(const f32x4*)(bqkv + h * 32 + 4 * g);
      f32x4 b1 = *(const f32x4*)(bqkv + h * 32 + 16 + 4 * g);
      wr4(sw, c, 4 * g, qa0 + b0);        // scrQ[q-local][d]
      wr4(sw, c, 16 + 4 * g, qa1 + b1);
    }
    const bf16x8 qf = *(const bf16x8*)(sw + sidx(c, g * 8));  // Q B-frag

    // ---- K^T = Wk^T @ X^T (d=32 x tok=64) ----
    f32x4 k00 = z, k01 = z, k02 = z, k03 = z, k10 = z, k11 = z, k12 = z, k13 = z;
    {
      const unsigned short* wk = WqkvT + (192 + h * 32) * 192 + g * 8;
      #pragma unroll
      for (int ks = 0; ks < 6; ++ks) {
        bf16x8 a0 = *(const bf16x8*)(wk + c * 192 + ks * 32);
        bf16x8 a1 = *(const bf16x8*)(wk + (16 + c) * 192 + ks * 32);
        const int xc = (ks * 32 + g * 8) ^ cq3;
        bf16x8 x0 = *(const bf16x8*)(Xs + (c) * XST + xc);
        bf16x8 x1 = *(const bf16x8*)(Xs + (16 + c) * XST + xc);
        bf16x8 x2 = *(const bf16x8*)(Xs + (32 + c) * XST + xc);
        bf16x8 x3 = *(const bf16x8*)(Xs + (48 + c) * XST + xc);
        k00 = MFMA(a0, x0, k00); k01 = MFMA(a0, x1, k01);
        k02 = MFMA(a0, x2, k02); k03 = MFMA(a0, x3, k03);
        k10 = MFMA(a1, x0, k10); k11 = MFMA(a1, x1, k11);
        k12 = MFMA(a1, x2, k12); k13 = MFMA(a1, x3, k13);
      }
    }
    f32x4 bk0 = *(const f32x4*)(bqkv + 192 + h * 32 + 4 * g);
    f32x4 bk1 = *(const f32x4*)(bqkv + 192 + h * 32 + 16 + 4 * g);

    // per t: scratch round-trip -> K A-frag -> S^T tile (wave-private ordering)
    f32x4 s0, s1, s2, s3;
    wr4(sw, c, 4 * g, k00 + bk0); wr4(sw, c, 16 + 4 * g, k10 + bk1);
    s0 = MFMA(*(const bf16x8*)(sw + sidx(c, g * 8)), qf, z);
    wr4(sw, c, 4 * g, k01 + bk0); wr4(sw, c, 16 + 4 * g, k11 + bk1);
    s1 = MFMA(*(const bf16x8*)(sw + sidx(c, g * 8)), qf, z);
    wr4(sw, c, 4 * g, k02 + bk0); wr4(sw, c, 16 + 4 * g, k12 + bk1);
    s2 = MFMA(*(const bf16x8*)(sw + sidx(c, g * 8)), qf, z);
    wr4(sw, c, 4 * g, k03 + bk0); wr4(sw, c, 16 + 4 * g, k13 + bk1);
    s3 = MFMA(*(const bf16x8*)(sw + sidx(c, g * 8)), qf, z);

    // ---- softmax: lane holds S^T[k=16t+4g+r][q=mt16+c] (v2-verified) ----
    float p[16];
    float mx = -3e38f;
    #pragma unroll
    for (int i = 0; i < 16; ++i) {
      const int t = i >> 2, r = i & 3;
      const int k = t * 16 + g * 4 + r;
      const float sv = (t == 0) ? s0[r] : (t == 1) ? s1[r] : (t == 2) ? s2[r] : s3[r];
      const float b = biasF[kb6[i] + qoff6 + h];
      const float lg = (qvalid && (k < 49)) ? fmaf(sv, SCALE, b) : -1e30f;
      p[i] = lg;
      mx = fmaxf(mx, lg);
    }
    mx = fmaxf(mx, __shfl_xor(mx, 16));
    mx = fmaxf(mx, __shfl_xor(mx, 32));
    float sum = 0.f;
    #pragma unroll
    for (int i = 0; i < 16; ++i) { p[i] = __expf(p[i] - mx); sum += p[i]; }
    sum += __shfl_xor(sum, 16);
    sum += __shfl_xor(sum, 32);
    const float inv = 1.0f / sum;
    #pragma unroll
    for (int t = 0; t < 4; ++t) {
      u16x4 pk;
      #pragma unroll
      for (int r = 0; r < 4; ++r) pk[r] = f2bf(p[t * 4 + r] * inv);
      *(u16x4*)(sw + sidx(c, t * 16 + 4 * g)) = pk;   // scrP[q-local][k]
    }
    const bf16x8 pf0 = *(const bf16x8*)(sw + sidx(c, g * 8));        // P^T B-frags
    const bf16x8 pf1 = *(const bf16x8*)(sw + sidx(c, 32 + g * 8));

    // ---- V^T = Wv^T @ X^T (d=32 x tok=64) ----
    f32x4 v00 = z, v01 = z, v02 = z, v03 = z, v10 = z, v11 = z, v12 = z, v13 = z;
    {
      const unsigned short* wv = WqkvT + (384 + h * 32) * 192 + g * 8;
      #pragma unroll
      for (int ks = 0; ks < 6; ++ks) {
        bf16x8 a0 = *(const bf16x8*)(wv + c * 192 + ks * 32);
        bf16x8 a1 = *(const bf16x8*)(wv + (16 + c) * 192 + ks * 32);
        const int xc = (ks * 32 + g * 8) ^ cq3;
        bf16x8 x0 = *(const bf16x8*)(Xs + (c) * XST + xc);
        bf16x8 x1 = *(const bf16x8*)(Xs + (16 + c) * XST + xc);
        bf16x8 x2 = *(const bf16x8*)(Xs + (32 + c) * XST + xc);
        bf16x8 x3 = *(const bf16x8*)(Xs + (48 + c) * XST + xc);
        v00 = MFMA(a0, x0, v00); v01 = MFMA(a0, x1, v01);
        v02 = MFMA(a0, x2, v02); v03 = MFMA(a0, x3, v03);
        v10 = MFMA(a1, x0, v10); v11 = MFMA(a1, x1, v11);
        v12 = MFMA(a1, x2, v12); v13 = MFMA(a1, x3, v13);
      }
    }
    f32x4 bv0 = *(const f32x4*)(bqkv + 384 + h * 32 + 4 * g);
    f32x4 bv1 = *(const f32x4*)(bqkv + 384 + h * 32 + 16 + 4 * g);

    // per d-half i: scrV[d-local][tok] -> V^T A-frags -> O^T -> AO
    #pragma unroll
    for (int i2 = 0; i2 < 2; ++i2) {
      f32x4 t0 = (i2 ? v10 : v00) + (i2 ? bv1 : bv0);
      f32x4 t1 = (i2 ? v11 : v01) + (i2 ? bv1 : bv0);
      f32x4 t2 = (i2 ? v12 : v02) + (i2 ? bv1 : bv0);
      f32x4 t3 = (i2 ? v13 : v03) + (i2 ? bv1 : bv0);
      #pragma unroll
      for (int r = 0; r < 4; ++r) {
        sw[sidx(4 * g + r, 0 * 16 + c)] = f2bf(t0[r]);
        sw[sidx(4 * g + r, 1 * 16 + c)] = f2bf(t1[r]);
        sw[sidx(4 * g + r, 2 * 16 + c)] = f2bf(t2[r]);
        sw[sidx(4 * g + r, 3 * 16 + c)] = f2bf(t3[r]);
      }
      bf16x8 vf0 = *(const bf16x8*)(sw + sidx(c, g * 8));
      bf16x8 vf1 = *(const bf16x8*)(sw + sidx(c, 32 + g * 8));
      f32x4 o = MFMA(vf0, pf0, z);
      o = MFMA(vf1, pf1, o);
      #pragma unroll
      for (int r = 0; r < 4; ++r)
        AO[xidx(mt * 16 + c, h * 32 + i2 * 16 + 4 * g + r)] = f2bf(o[r]);
    }
  }
  __syncthreads();  // barrier 2: AO complete

  // ---- Phase C: Y = AO @ Wo + bo. Wave (mt, hw) -> rows mt*16.., cols hw*96.. ----
  {
    bf16x8 af[6];
    #pragma unroll
    for (int ks = 0; ks < 6; ++ks)
      af[ks] = *(const bf16x8*)(AO + (mt * 16 + c) * XST + ((ks * 32 + g * 8) ^ cq3));
    float* og = out + (size_t)wb * 9408;
    #pragma unroll
    for (int ot = 0; ot < 6; ++ot) {
      const int ocol = hw * 96 + ot * 16 + c;
      const unsigned short* wo = WoT + ocol * 192 + g * 8;
      f32x4 acc = z;
      #pragma unroll
      for (int ks = 0; ks < 6; ++ks)
        acc = MFMA(af[ks], *(const bf16x8*)(wo + ks * 32), acc);
      const float bb = bo[ocol];
      #pragma unroll
      for (int r = 0; r < 4; ++r) {
        const int qr = mt * 16 + 4 * g + r;
        if (qr < 49) og[qr * 192 + ocol] = acc[r] + bb;
      }
    }
  }
}

extern "C" void kernel_launch(void* const* d_in, const int* in_sizes, int n_in,
                              void* d_out, int out_size, void* d_ws, size_t ws_size,
                              hipStream_t stream) {
  const float* X    = (const float*)d_in[0];
  const float* Wqkv = (const float*)d_in[1];
  const float* bqkv = (const float*)d_in[2];
  const float* Wo   = (const float*)d_in[3];
  const float* bo   = (const float*)d_in[4];
  const float* btab = (const float*)d_in[5];

  unsigned short* WqkvT = (unsigned short*)d_ws;   // 576*192 bf16
  unsigned short* WoT   = WqkvT + 576 * 192;       // 192*192 bf16

  wprep<<<432, 256, 0, stream>>>(Wqkv, Wo, WqkvT, WoT);
  winmsa<<<4096, 512, 0, stream>>>(X, WqkvT, bqkv, WoT, bo, btab, (float*)d_out);
}

// Round 4
// 308.851 us; speedup vs baseline: 3.6548x; 3.6548x over previous
//
#include <hip/hip_runtime.h>
#include <hip/hip_bf16.h>

// WinMSA for MI355X (gfx950), v4: 3-kernel pipeline through d_ws.
//   K1: qkv = X @ Wqkv + b   (bf16 GEMM, LDS-staged weight chunks, dbuf)
//   K2: per-window attention (K/V LDS-staged, AO overwrites Q cols of qkv)
//   K3: out = AO @ Wo + bo   (WoT staged once per block)
// Falls back to the verified v1 fused kernel if ws_size < ~232 MB.

typedef __attribute__((ext_vector_type(4))) float f32x4;
typedef __attribute__((ext_vector_type(8))) short bf16x8;
typedef __attribute__((ext_vector_type(4))) unsigned short u16x4;

#define SCALE 0.17677669529663689f  // 32^-0.5
#define MFMA(a, b, acc) __builtin_amdgcn_mfma_f32_16x16x32_bf16(a, b, acc, 0, 0, 0)

__device__ __forceinline__ unsigned short f2bf(float f) {
  union { float f; unsigned int u; } v; v.f = f;
  return (unsigned short)((v.u + 0x7FFFu + ((v.u >> 16) & 1u)) >> 16);  // RNE
}

// Pre-kernel: transpose weights to bf16 [out][in].
__global__ void wprep(const float* __restrict__ Wqkv, const float* __restrict__ Wo,
                      unsigned short* __restrict__ WqkvT, unsigned short* __restrict__ WoT) {
  int i = blockIdx.x * 256 + threadIdx.x;
  if (i < 576 * 192) { int n = i / 192, k = i % 192; WqkvT[i] = f2bf(Wqkv[k * 576 + n]); }
  if (i < 192 * 192) { int n = i / 192, k = i % 192; WoT[i]   = f2bf(Wo[k * 192 + n]); }
}

// ---------------- K1: qkv GEMM ----------------
// grid 3136 (64 rows each), 512 threads. Wave (mt, nh): 16 rows x 32 cols/chunk.
__global__ __launch_bounds__(512, 4)
void qkv_gemm(const float* __restrict__ X, const unsigned short* __restrict__ WqkvT,
              const float* __restrict__ bqkv, unsigned short* __restrict__ qkv) {
  __shared__ __align__(16) unsigned short Bs[2][64 * 200];  // weight chunk, dbuf, padded
  __shared__ __align__(16) unsigned short scr[8][16 * 40];  // per-wave store bounce

  const int tid = threadIdx.x, w8 = tid >> 6, lane = tid & 63;
  const int g = lane >> 4, c = lane & 15;
  const int mt = w8 & 3, nh = w8 >> 2;
  const size_t bm = (size_t)blockIdx.x * 64;
  const f32x4 z = {0.f, 0.f, 0.f, 0.f};

  // A-fragments (16 rows of X per wave) in registers, f32 -> bf16
  bf16x8 af[6];
  {
    const float* xr = X + (bm + mt * 16 + c) * 192;
    #pragma unroll
    for (int ks = 0; ks < 6; ++ks) {
      f32x4 lo = *(const f32x4*)(xr + ks * 32 + g * 8);
      f32x4 hi = *(const f32x4*)(xr + ks * 32 + g * 8 + 4);
      bf16x8 a;
      a[0] = (short)f2bf(lo[0]); a[1] = (short)f2bf(lo[1]);
      a[2] = (short)f2bf(lo[2]); a[3] = (short)f2bf(lo[3]);
      a[4] = (short)f2bf(hi[0]); a[5] = (short)f2bf(hi[1]);
      a[6] = (short)f2bf(hi[2]); a[7] = (short)f2bf(hi[3]);
      af[ks] = a;
    }
  }

  // stage chunk 0 (reg -> LDS, padded rows)
  uint4 st[3];
  #pragma unroll
  for (int jj = 0; jj < 3; ++jj) {
    int j = tid + jj * 512;
    st[jj] = *(const uint4*)(WqkvT + (j / 24) * 192 + (j % 24) * 8);
  }
  #pragma unroll
  for (int jj = 0; jj < 3; ++jj) {
    int j = tid + jj * 512;
    *(uint4*)(&Bs[0][(j / 24) * 200 + (j % 24) * 8]) = st[jj];
  }
  __syncthreads();

  unsigned short* sw = scr[w8];
  for (int nc = 0; nc < 9; ++nc) {
    const int cur = nc & 1;
    if (nc < 8) {  // prefetch next chunk into regs (hidden under MFMA)
      #pragma unroll
      for (int jj = 0; jj < 3; ++jj) {
        int j = tid + jj * 512;
        st[jj] = *(const uint4*)(WqkvT + (nc + 1) * 12288 + (j / 24) * 192 + (j % 24) * 8);
      }
    }
    f32x4 a0 = z, a1 = z;
    const unsigned short* b0 = &Bs[cur][(nh * 32 + c) * 200];
    const unsigned short* b1 = b0 + 16 * 200;
    #pragma unroll
    for (int ks = 0; ks < 6; ++ks) {
      a0 = MFMA(af[ks], *(const bf16x8*)(b0 + ks * 32 + g * 8), a0);
      a1 = MFMA(af[ks], *(const bf16x8*)(b1 + ks * 32 + g * 8), a1);
    }
    // bias + bounce (D row=4g+r, col=c) -> coalesced 16B store
    const int col0 = nc * 64 + nh * 32 + c;
    const float bb0 = bqkv[col0], bb1 = bqkv[col0 + 16];
    #pragma unroll
    for (int r = 0; r < 4; ++r) {
      sw[(4 * g + r) * 40 + c]      = f2bf(a0[r] + bb0);
      sw[(4 * g + r) * 40 + 16 + c] = f2bf(a1[r] + bb1);
    }
    uint4 ov = *(const uint4*)(sw + c * 40 + g * 8);
    *(uint4*)(qkv + (bm + mt * 16 + c) * 576 + nc * 64 + nh * 32 + g * 8) = ov;

    if (nc < 8) {  // write next chunk into the other buffer
      #pragma unroll
      for (int jj = 0; jj < 3; ++jj) {
        int j = tid + jj * 512;
        *(uint4*)(&Bs[cur ^ 1][(j / 24) * 200 + (j % 24) * 8]) = st[jj];
      }
    }
    __syncthreads();
  }
}

// ---------------- K2: windowed attention ----------------
// grid 4096 (1 window), 512 threads. Wave (mt, hw): heads hw*3..hw*3+2.
// Reads Q/K/V from qkv; writes attn-out into qkv cols [0,192) (Q is dead).
__global__ __launch_bounds__(512, 4)
void attn_win(unsigned short* __restrict__ qkv, const float* __restrict__ btab) {
  __shared__ __align__(16) unsigned short Ks[64 * 200];   // K rows [tok][d192], padded
  __shared__ __align__(16) unsigned short Vt[192 * 72];   // V^T [d][tok]
  __shared__ __align__(16) unsigned short scr[8][1152];   // per-wave P / O bounce
  __shared__ float biasF[1014];

  const int tid = threadIdx.x, w8 = tid >> 6, lane = tid & 63;
  const int g = lane >> 4, c = lane & 15;
  const int mt = w8 & 3, hw = w8 >> 2;
  const size_t tokbase = (size_t)blockIdx.x * 49;
  const f32x4 z = {0.f, 0.f, 0.f, 0.f};

  for (int j = tid; j < 1014; j += 512) biasF[j] = btab[j];
  // zero K pad rows 49..63 (cols < 192)
  for (int j = tid; j < 360; j += 512) {
    uint4 zz = {0, 0, 0, 0};
    *(uint4*)(&Ks[(49 + j / 24) * 200 + (j % 24) * 8]) = zz;
  }
  // zero V^T pad token cols 49..63
  for (int j = tid; j < 2880; j += 512) Vt[(j / 15) * 72 + 49 + j % 15] = 0;
  // K rows: straight copy
  for (int j = tid; j < 1176; j += 512) {
    int row = j / 24, ch = j % 24;
    *(uint4*)(&Ks[row * 200 + ch * 8]) =
        *(const uint4*)(qkv + (tokbase + row) * 576 + 192 + ch * 8);
  }
  // V: transpose-scatter [tok][d] -> Vt[d][tok]
  for (int j = tid; j < 1176; j += 512) {
    int row = j / 24, ch = j % 24;
    uint4 v = *(const uint4*)(qkv + (tokbase + row) * 576 + 384 + ch * 8);
    const unsigned short* e = (const unsigned short*)&v;
    #pragma unroll
    for (int k = 0; k < 8; ++k) Vt[(ch * 8 + k) * 72 + row] = e[k];
  }
  __syncthreads();  // the only barrier

  const int qbase = mt * 16;
  const int q = qbase + c;
  const bool qvalid = q < 49;
  const int qc = qvalid ? q : 48;
  const int qoff6 = ((6 - qc / 7) * 13 + (6 - qc % 7)) * 6;
  int kb6[16];
  #pragma unroll
  for (int i = 0; i < 16; ++i) {
    int k = (i >> 2) * 16 + g * 4 + (i & 3);
    int kk = k < 49 ? k : 48;
    kb6[i] = ((kk / 7) * 13 + (kk % 7)) * 6;
  }
  unsigned short* Pw = scr[w8];

  for (int hi = 0; hi < 3; ++hi) {
    const int h = hw * 3 + hi;
    // Q B-frag direct from global (own window rows; clamped)
    const bf16x8 bq = *(const bf16x8*)(qkv + (tokbase + qc) * 576 + h * 32 + g * 8);
    const int cofs = h * 32 + g * 8;
    f32x4 s0 = MFMA(*(const bf16x8*)(Ks + (c) * 200 + cofs), bq, z);
    f32x4 s1 = MFMA(*(const bf16x8*)(Ks + (16 + c) * 200 + cofs), bq, z);
    f32x4 s2 = MFMA(*(const bf16x8*)(Ks + (32 + c) * 200 + cofs), bq, z);
    f32x4 s3 = MFMA(*(const bf16x8*)(Ks + (48 + c) * 200 + cofs), bq, z);

    // softmax: lane holds S^T[k=16t+4g+r][q=qbase+c]  (v2-verified)
    float p[16];
    float mx = -3e38f;
    #pragma unroll
    for (int i = 0; i < 16; ++i) {
      const int t = i >> 2, r = i & 3;
      const int k = t * 16 + g * 4 + r;
      const float sv = (t == 0) ? s0[r] : (t == 1) ? s1[r] : (t == 2) ? s2[r] : s3[r];
      const float b = biasF[kb6[i] + qoff6 + h];
      const float lg = (qvalid && (k < 49)) ? fmaf(sv, SCALE, b) : -1e30f;
      p[i] = lg;
      mx = fmaxf(mx, lg);
    }
    mx = fmaxf(mx, __shfl_xor(mx, 16));
    mx = fmaxf(mx, __shfl_xor(mx, 32));
    float sum = 0.f;
    #pragma unroll
    for (int i = 0; i < 16; ++i) { p[i] = __expf(p[i] - mx); sum += p[i]; }
    sum += __shfl_xor(sum, 16);
    sum += __shfl_xor(sum, 32);
    const float inv = 1.0f / sum;
    #pragma unroll
    for (int t = 0; t < 4; ++t) {
      u16x4 pk;
      #pragma unroll
      for (int r = 0; r < 4; ++r) pk[r] = f2bf(p[t * 4 + r] * inv);
      *(u16x4*)(Pw + c * 72 + t * 16 + g * 4) = pk;  // P[q-local=c][k]
    }

    // PV: A = P (wave-private), B = Vt[d][tok]
    f32x4 o0 = z, o1 = z;
    #pragma unroll
    for (int ks = 0; ks < 2; ++ks) {
      const bf16x8 ap = *(const bf16x8*)(Pw + c * 72 + ks * 32 + g * 8);
      const bf16x8 v0 = *(const bf16x8*)(Vt + (h * 32 + c) * 72 + ks * 32 + g * 8);
      const bf16x8 v1 = *(const bf16x8*)(Vt + (h * 32 + 16 + c) * 72 + ks * 32 + g * 8);
      o0 = MFMA(ap, v0, o0);
      o1 = MFMA(ap, v1, o1);
    }
    // O bounce (rows 4g+r, d cols c/16+c) -> coalesced 16B global store into qkv Q-cols
    #pragma unroll
    for (int r = 0; r < 4; ++r) {
      Pw[(4 * g + r) * 72 + c]      = f2bf(o0[r]);
      Pw[(4 * g + r) * 72 + 16 + c] = f2bf(o1[r]);
    }
    uint4 ov = *(const uint4*)(Pw + c * 72 + g * 8);
    if (qvalid)
      *(uint4*)(qkv + (tokbase + q) * 576 + h * 32 + g * 8) = ov;
  }
}

// ---------------- K3: output projection ----------------
// grid 3136 (64 rows), 512 threads. Wave (mt, nh): 16 rows x 96 cols.
__global__ __launch_bounds__(512, 4)
void out_gemm(const unsigned short* __restrict__ qkv, const unsigned short* __restrict__ WoT,
              const float* __restrict__ bo, float* __restrict__ out) {
  __shared__ __align__(16) unsigned short Ws[192 * 200];  // 76.8 KB, padded

  const int tid = threadIdx.x, w8 = tid >> 6, lane = tid & 63;
  const int g = lane >> 4, c = lane & 15;
  const int mt = w8 & 3, nh = w8 >> 2;
  const size_t bm = (size_t)blockIdx.x * 64;
  const f32x4 z = {0.f, 0.f, 0.f, 0.f};

  for (int j = tid; j < 4608; j += 512) {  // 192 rows x 24 chunks of 16B
    int row = j / 24, ch = j % 24;
    *(uint4*)(&Ws[row * 200 + ch * 8]) = *(const uint4*)(WoT + row * 192 + ch * 8);
  }
  __syncthreads();

  bf16x8 af[6];
  #pragma unroll
  for (int ks = 0; ks < 6; ++ks)
    af[ks] = *(const bf16x8*)(qkv + (bm + mt * 16 + c) * 576 + ks * 32 + g * 8);

  #pragma unroll
  for (int nf = 0; nf < 6; ++nf) {
    const int col = nh * 96 + nf * 16 + c;
    const unsigned short* bp = Ws + col * 200;
    f32x4 acc = z;
    #pragma unroll
    for (int ks = 0; ks < 6; ++ks)
      acc = MFMA(af[ks], *(const bf16x8*)(bp + ks * 32 + g * 8), acc);
    const float bb = bo[col];
    #pragma unroll
    for (int r = 0; r < 4; ++r)
      out[(bm + mt * 16 + 4 * g + r) * 192 + col] = acc[r] + bb;
  }
}

// ---------------- Fallback: v1 fused kernel (verified, 454 us) ----------------
__global__ __launch_bounds__(512, 2)
void winmsa_fb(const float* __restrict__ X, const unsigned short* __restrict__ WqkvT,
               const float* __restrict__ bqkv, const unsigned short* __restrict__ WoT,
               const float* __restrict__ bo, const float* __restrict__ btab,
               float* __restrict__ out) {
  __shared__ __align__(16) unsigned short Xs[64 * 200];
  __shared__ __align__(16) unsigned short WtC[64 * 200];
  __shared__ __align__(16) unsigned short Qs[64 * 200];
  __shared__ __align__(16) unsigned short Ks2[64 * 200];
  __shared__ __align__(16) unsigned short Vt[192 * 72];

  const int tid = threadIdx.x, w8 = tid >> 6, lane = tid & 63;
  const int g = lane >> 4, c = lane & 15;
  const int mt = w8 & 3, half = w8 >> 2;
  const int wb = blockIdx.x;

  for (int i = tid; i < 1500; i += 512) ((unsigned int*)(Xs + 49 * 200))[i] = 0u;
  const float* Xg = X + (size_t)wb * 9408;
  for (int j = tid; j < 2352; j += 512) {
    f32x4 x4 = ((const f32x4*)Xg)[j];
    int f = j * 4, row = f / 192, col = f % 192;
    u16x4 p;
    p[0] = f2bf(x4[0]); p[1] = f2bf(x4[1]); p[2] = f2bf(x4[2]); p[3] = f2bf(x4[3]);
    *(u16x4*)(Xs + row * 200 + col) = p;
  }
  __syncthreads();

  for (int nc = 0; nc < 9; ++nc) {
    const unsigned short* Wg = WqkvT + nc * (64 * 192);
    #pragma unroll
    for (int jj = 0; jj < 3; ++jj) {
      int j = tid + jj * 512;
      uint4 v = ((const uint4*)Wg)[j];
      *(uint4*)(WtC + (j / 24) * 200 + (j % 24) * 8) = v;
    }
    __syncthreads();
    f32x4 a0 = {0.f, 0.f, 0.f, 0.f}, a1 = {0.f, 0.f, 0.f, 0.f};
    const unsigned short* ar = Xs + (mt * 16 + c) * 200;
    const unsigned short* b0 = WtC + (half * 32 + c) * 200;
    const unsigned short* b1 = b0 + 16 * 200;
    #pragma unroll
    for (int ks = 0; ks < 6; ++ks) {
      int ko = ks * 32 + g * 8;
      bf16x8 av = *(const bf16x8*)(ar + ko);
      a0 = MFMA(av, *(const bf16x8*)(b0 + ko), a0);
      a1 = MFMA(av, *(const bf16x8*)(b1 + ko), a1);
    }
    #pragma unroll
    for (int i = 0; i < 2; ++i) {
      f32x4 acc = i ? a1 : a0;
      int gcol = nc * 64 + half * 32 + i * 16 + c;
      float bias = bqkv[gcol];
      int rb = mt * 16 + g * 4;
      if (gcol < 192) {
        #pragma unroll
        for (int r = 0; r < 4; ++r) Qs[(rb + r) * 200 + gcol] = f2bf(acc[r] + bias);
      } else if (gcol < 384) {
        #pragma unroll
        for (int r = 0; r < 4; ++r) Ks2[(rb + r) * 200 + gcol - 192] = f2bf(acc[r] + bias);
      } else {
        u16x4 pv;
        #pragma unroll
        for (int r = 0; r < 4; ++r) pv[r] = f2bf(acc[r] + bias);
        *(u16x4*)(Vt + (gcol - 384) * 72 + rb) = pv;
      }
    }
    __syncthreads();
  }

  float* biasF = (float*)(WtC + 9216);
  for (int j = tid; j < 1014; j += 512) biasF[j] = btab[j];
  __syncthreads();

  unsigned short* Psw = WtC + w8 * 1152;
  const int qrow = mt * 16;
  for (int hi = 0; hi < 3; ++hi) {
    int h = half * 3 + hi;
    bf16x8 aq = *(const bf16x8*)(Qs + (qrow + c) * 200 + h * 32 + g * 8);
    f32x4 z = {0.f, 0.f, 0.f, 0.f};
    f32x4 s0 = MFMA(aq, *(const bf16x8*)(Ks2 + (c) * 200 + h * 32 + g * 8), z);
    f32x4 s1 = MFMA(aq, *(const bf16x8*)(Ks2 + (16 + c) * 200 + h * 32 + g * 8), z);
    f32x4 s2 = MFMA(aq, *(const bf16x8*)(Ks2 + (32 + c) * 200 + h * 32 + g * 8), z);
    f32x4 s3 = MFMA(aq, *(const bf16x8*)(Ks2 + (48 + c) * 200 + h * 32 + g * 8), z);
    auto logit = [&](float sv, int col, int r) -> float {
      if (r < 49 && col < 49) {
        int dy = col / 7 - r / 7 + 6;
        int dx = col % 7 - r % 7 + 6;
        return sv * SCALE + biasF[(dy * 13 + dx) * 6 + h];
      }
      return -1e30f;
    };
    #pragma unroll
    for (int reg = 0; reg < 4; ++reg) {
      int r = qrow + g * 4 + reg;
      float v0 = logit(s0[reg], c, r);
      float v1 = logit(s1[reg], 16 + c, r);
      float v2 = logit(s2[reg], 32 + c, r);
      float v3 = logit(s3[reg], 48 + c, r);
      float mx = fmaxf(fmaxf(v0, v1), fmaxf(v2, v3));
      mx = fmaxf(mx, __shfl_xor(mx, 1));
      mx = fmaxf(mx, __shfl_xor(mx, 2));
      mx = fmaxf(mx, __shfl_xor(mx, 4));
      mx = fmaxf(mx, __shfl_xor(mx, 8));
      v0 = __expf(v0 - mx); v1 = __expf(v1 - mx); v2 = __expf(v2 - mx); v3 = __expf(v3 - mx);
      float sm = v0 + v1 + v2 + v3;
      sm += __shfl_xor(sm, 1); sm += __shfl_xor(sm, 2);
      sm += __shfl_xor(sm, 4); sm += __shfl_xor(sm, 8);
      float inv = 1.0f / sm;
      int pr = (g * 4 + reg) * 72;
      Psw[pr + c] = f2bf(v0 * inv);
      Psw[pr + 16 + c] = f2bf(v1 * inv);
      Psw[pr + 32 + c] = f2bf(v2 * inv);
      Psw[pr + 48 + c] = f2bf(v3 * inv);
    }
    f32x4 o0 = {0.f, 0.f, 0.f, 0.f}, o1 = {0.f, 0.f, 0.f, 0.f};
    #pragma unroll
    for (int ks = 0; ks < 2; ++ks) {
      bf16x8 ap = *(const bf16x8*)(Psw + c * 72 + ks * 32 + g * 8);
      bf16x8 v0 = *(const bf16x8*)(Vt + (h * 32 + c) * 72 + ks * 32 + g * 8);
      bf16x8 v1 = *(const bf16x8*)(Vt + (h * 32 + 16 + c) * 72 + ks * 32 + g * 8);
      o0 = MFMA(ap, v0, o0);
      o1 = MFMA(ap, v1, o1);
    }
    int rb = qrow + g * 4;
    #pragma unroll
    for (int r = 0; r < 4; ++r) {
      Xs[(rb + r) * 200 + h * 32 + c] = f2bf(o0[r]);
      Xs[(rb + r) * 200 + h * 32 + 16 + c] = f2bf(o1[r]);
    }
  }
  __syncthreads();

  for (int nc = 0; nc < 3; ++nc) {
    const unsigned short* Wg = WoT + nc * (64 * 192);
    #pragma unroll
    for (int jj = 0; jj < 3; ++jj) {
      int j = tid + jj * 512;
      uint4 v = ((const uint4*)Wg)[j];
      *(uint4*)(WtC + (j / 24) * 200 + (j % 24) * 8) = v;
    }
    __syncthreads();
    f32x4 a0 = {0.f, 0.f, 0.f, 0.f}, a1 = {0.f, 0.f, 0.f, 0.f};
    const unsigned short* ar = Xs + (mt * 16 + c) * 200;
    const unsigned short* b0 = WtC + (half * 32 + c) * 200;
    const unsigned short* b1 = b0 + 16 * 200;
    #pragma unroll
    for (int ks = 0; ks < 6; ++ks) {
      int ko = ks * 32 + g * 8;
      bf16x8 av = *(const bf16x8*)(ar + ko);
      a0 = MFMA(av, *(const bf16x8*)(b0 + ko), a0);
      a1 = MFMA(av, *(const bf16x8*)(b1 + ko), a1);
    }
    float* og = out + (size_t)wb * 9408;
    #pragma unroll
    for (int i = 0; i < 2; ++i) {
      f32x4 acc = i ? a1 : a0;
      int gcol = nc * 64 + half * 32 + i * 16 + c;
      float bb = bo[gcol];
      #pragma unroll
      for (int r = 0; r < 4; ++r) {
        int rr = mt * 16 + g * 4 + r;
        if (rr < 49) og[rr * 192 + gcol] = acc[r] + bb;
      }
    }
    __syncthreads();
  }
}

extern "C" void kernel_launch(void* const* d_in, const int* in_sizes, int n_in,
                              void* d_out, int out_size, void* d_ws, size_t ws_size,
                              hipStream_t stream) {
  (void)in_sizes; (void)n_in; (void)out_size;
  const float* X    = (const float*)d_in[0];
  const float* Wqkv = (const float*)d_in[1];
  const float* bqkv = (const float*)d_in[2];
  const float* Wo   = (const float*)d_in[3];
  const float* bo   = (const float*)d_in[4];
  const float* btab = (const float*)d_in[5];

  unsigned short* WqkvT = (unsigned short*)d_ws;   // 576*192 bf16 = 221184 B
  unsigned short* WoT   = WqkvT + 576 * 192;       // 192*192 bf16 =  73728 B

  wprep<<<432, 256, 0, stream>>>(Wqkv, Wo, WqkvT, WoT);

  const size_t need = 294912 + (size_t)200704 * 576 * 2;  // +231.2 MB qkv
  if (ws_size >= need) {
    unsigned short* qkv = WoT + 192 * 192;
    qkv_gemm<<<3136, 512, 0, stream>>>(X, WqkvT, bqkv, qkv);
    attn_win<<<4096, 512, 0, stream>>>(qkv, btab);
    out_gemm<<<3136, 512, 0, stream>>>(qkv, WoT, bo, (float*)d_out);
  } else {
    winmsa_fb<<<4096, 512, 0, stream>>>(X, WqkvT, bqkv, WoT, bo, btab, (float*)d_out);
  }
}

// Round 5
// 290.667 us; speedup vs baseline: 3.8834x; 1.0626x over previous
//
#include <hip/hip_runtime.h>
#include <hip/hip_bf16.h>

// WinMSA for MI355X (gfx950), v5: 3-kernel pipeline through d_ws.
//   K1: qkv = X @ Wqkv + b   (128-row blocks, LDS dbuf weight chunks)
//   K2: per-window attention (K/V LDS-staged, AO overwrites Q cols of qkv)
//   K3: out = AO @ Wo + bo   (128-row blocks, WoT staged once)

typedef __attribute__((ext_vector_type(4))) float f32x4;
typedef __attribute__((ext_vector_type(8))) short bf16x8;
typedef __attribute__((ext_vector_type(4))) unsigned short u16x4;

#define SCALE 0.17677669529663689f  // 32^-0.5
#define MFMA(a, b, acc) __builtin_amdgcn_mfma_f32_16x16x32_bf16(a, b, acc, 0, 0, 0)

__device__ __forceinline__ unsigned short f2bf(float f) {
  union { float f; unsigned int u; } v; v.f = f;
  return (unsigned short)((v.u + 0x7FFFu + ((v.u >> 16) & 1u)) >> 16);  // RNE
}

// Pre-kernel: transpose weights to bf16 [out][in].
__global__ void wprep(const float* __restrict__ Wqkv, const float* __restrict__ Wo,
                      unsigned short* __restrict__ WqkvT, unsigned short* __restrict__ WoT) {
  int i = blockIdx.x * 256 + threadIdx.x;
  if (i < 576 * 192) { int n = i / 192, k = i % 192; WqkvT[i] = f2bf(Wqkv[k * 576 + n]); }
  if (i < 192 * 192) { int n = i / 192, k = i % 192; WoT[i]   = f2bf(Wo[k * 192 + n]); }
}

// ---------------- K1: qkv GEMM, 128 rows/block ----------------
// grid 1568, 512 threads. Wave w8 owns rows w8*16..w8*16+15, all 64 chunk cols.
__global__ __launch_bounds__(512, 4)
void qkv_gemm(const float* __restrict__ X, const unsigned short* __restrict__ WqkvT,
              const float* __restrict__ bqkv, unsigned short* __restrict__ qkv) {
  __shared__ __align__(16) unsigned short Bs[2][64 * 200];  // weight chunk dbuf, padded
  __shared__ __align__(16) unsigned short scr[8][16 * 72];  // per-wave store bounce

  const int tid = threadIdx.x, w8 = tid >> 6, lane = tid & 63;
  const int g = lane >> 4, c = lane & 15;
  const size_t bm = (size_t)blockIdx.x * 128;
  const f32x4 z = {0.f, 0.f, 0.f, 0.f};

  // A-fragments: 16 rows of X per wave, f32 -> bf16, register-resident
  bf16x8 af[6];
  {
    const float* xr = X + (bm + w8 * 16 + c) * 192;
    #pragma unroll
    for (int ks = 0; ks < 6; ++ks) {
      f32x4 lo = *(const f32x4*)(xr + ks * 32 + g * 8);
      f32x4 hi = *(const f32x4*)(xr + ks * 32 + g * 8 + 4);
      bf16x8 a;
      a[0] = (short)f2bf(lo[0]); a[1] = (short)f2bf(lo[1]);
      a[2] = (short)f2bf(lo[2]); a[3] = (short)f2bf(lo[3]);
      a[4] = (short)f2bf(hi[0]); a[5] = (short)f2bf(hi[1]);
      a[6] = (short)f2bf(hi[2]); a[7] = (short)f2bf(hi[3]);
      af[ks] = a;
    }
  }

  // stage chunk 0
  uint4 st[3];
  #pragma unroll
  for (int jj = 0; jj < 3; ++jj) {
    int j = tid + jj * 512;
    st[jj] = *(const uint4*)(WqkvT + (j / 24) * 192 + (j % 24) * 8);
  }
  #pragma unroll
  for (int jj = 0; jj < 3; ++jj) {
    int j = tid + jj * 512;
    *(uint4*)(&Bs[0][(j / 24) * 200 + (j % 24) * 8]) = st[jj];
  }
  __syncthreads();

  unsigned short* sw = scr[w8];
  for (int nc = 0; nc < 9; ++nc) {
    const int cur = nc & 1;
    if (nc < 8) {  // prefetch next chunk into regs (hidden under 24 MFMA)
      #pragma unroll
      for (int jj = 0; jj < 3; ++jj) {
        int j = tid + jj * 512;
        st[jj] = *(const uint4*)(WqkvT + (nc + 1) * 12288 + (j / 24) * 192 + (j % 24) * 8);
      }
    }
    f32x4 acc[4] = {z, z, z, z};
    #pragma unroll
    for (int ks = 0; ks < 6; ++ks) {
      const unsigned short* bp = &Bs[cur][c * 200 + ks * 32 + g * 8];
      #pragma unroll
      for (int nf = 0; nf < 4; ++nf)
        acc[nf] = MFMA(af[ks], *(const bf16x8*)(bp + nf * 16 * 200), acc[nf]);
    }
    // bias + bounce (tile rows 4g+r, col c) -> coalesced 16B stores
    #pragma unroll
    for (int nf = 0; nf < 4; ++nf) {
      const float bb = bqkv[nc * 64 + nf * 16 + c];
      #pragma unroll
      for (int r = 0; r < 4; ++r)
        sw[(4 * g + r) * 72 + nf * 16 + c] = f2bf(acc[nf][r] + bb);
    }
    uint4 o0 = *(const uint4*)(sw + c * 72 + g * 8);
    uint4 o1 = *(const uint4*)(sw + c * 72 + 32 + g * 8);
    unsigned short* qp = qkv + (bm + w8 * 16 + c) * 576 + nc * 64;
    *(uint4*)(qp + g * 8)      = o0;
    *(uint4*)(qp + 32 + g * 8) = o1;

    if (nc < 8) {
      #pragma unroll
      for (int jj = 0; jj < 3; ++jj) {
        int j = tid + jj * 512;
        *(uint4*)(&Bs[cur ^ 1][(j / 24) * 200 + (j % 24) * 8]) = st[jj];
      }
    }
    __syncthreads();
  }
}

// ---------------- K2: windowed attention ----------------
// grid 4096 (1 window), 512 threads. Wave (mt, hw): heads hw*3..hw*3+2.
// Reads Q/K/V from qkv; writes attn-out into qkv cols [0,192) (Q is dead).
__global__ __launch_bounds__(512, 4)
void attn_win(unsigned short* __restrict__ qkv, const float* __restrict__ btab) {
  __shared__ __align__(16) unsigned short Ks[64 * 200];   // K rows [tok][d192], padded
  __shared__ __align__(16) unsigned short Vt[192 * 72];   // V^T [d][tok]
  __shared__ __align__(16) unsigned short scr[8][1152];   // per-wave P / O bounce
  __shared__ float biasF[1014];

  const int tid = threadIdx.x, w8 = tid >> 6, lane = tid & 63;
  const int g = lane >> 4, c = lane & 15;
  const int mt = w8 & 3, hw = w8 >> 2;
  const size_t tokbase = (size_t)blockIdx.x * 49;
  const f32x4 z = {0.f, 0.f, 0.f, 0.f};

  for (int j = tid; j < 1014; j += 512) biasF[j] = btab[j];
  for (int j = tid; j < 360; j += 512) {      // zero K pad rows 49..63
    uint4 zz = {0, 0, 0, 0};
    *(uint4*)(&Ks[(49 + j / 24) * 200 + (j % 24) * 8]) = zz;
  }
  for (int j = tid; j < 2880; j += 512) Vt[(j / 15) * 72 + 49 + j % 15] = 0;  // V^T pad cols
  for (int j = tid; j < 1176; j += 512) {     // K rows: straight copy
    int row = j / 24, ch = j % 24;
    *(uint4*)(&Ks[row * 200 + ch * 8]) =
        *(const uint4*)(qkv + (tokbase + row) * 576 + 192 + ch * 8);
  }
  for (int j = tid; j < 1176; j += 512) {     // V: transpose-scatter -> Vt[d][tok]
    int row = j / 24, ch = j % 24;
    uint4 v = *(const uint4*)(qkv + (tokbase + row) * 576 + 384 + ch * 8);
    const unsigned short* e = (const unsigned short*)&v;
    #pragma unroll
    for (int k = 0; k < 8; ++k) Vt[(ch * 8 + k) * 72 + row] = e[k];
  }
  __syncthreads();  // the only barrier

  const int qbase = mt * 16;
  const int q = qbase + c;
  const bool qvalid = q < 49;
  const int qc = qvalid ? q : 48;
  const int qoff6 = ((6 - qc / 7) * 13 + (6 - qc % 7)) * 6;
  int kb6[16];
  #pragma unroll
  for (int i = 0; i < 16; ++i) {
    int k = (i >> 2) * 16 + g * 4 + (i & 3);
    int kk = k < 49 ? k : 48;
    kb6[i] = ((kk / 7) * 13 + (kk % 7)) * 6;
  }
  unsigned short* Pw = scr[w8];

  for (int hi = 0; hi < 3; ++hi) {
    const int h = hw * 3 + hi;
    const bf16x8 bq = *(const bf16x8*)(qkv + (tokbase + qc) * 576 + h * 32 + g * 8);
    const int cofs = h * 32 + g * 8;
    f32x4 s0 = MFMA(*(const bf16x8*)(Ks + (c) * 200 + cofs), bq, z);
    f32x4 s1 = MFMA(*(const bf16x8*)(Ks + (16 + c) * 200 + cofs), bq, z);
    f32x4 s2 = MFMA(*(const bf16x8*)(Ks + (32 + c) * 200 + cofs), bq, z);
    f32x4 s3 = MFMA(*(const bf16x8*)(Ks + (48 + c) * 200 + cofs), bq, z);

    // softmax: lane holds S^T[k=16t+4g+r][q=qbase+c]  (verified layout)
    float p[16];
    float mx = -3e38f;
    #pragma unroll
    for (int i = 0; i < 16; ++i) {
      const int t = i >> 2, r = i & 3;
      const int k = t * 16 + g * 4 + r;
      const float sv = (t == 0) ? s0[r] : (t == 1) ? s1[r] : (t == 2) ? s2[r] : s3[r];
      const float b = biasF[kb6[i] + qoff6 + h];
      const float lg = (qvalid && (k < 49)) ? fmaf(sv, SCALE, b) : -1e30f;
      p[i] = lg;
      mx = fmaxf(mx, lg);
    }
    mx = fmaxf(mx, __shfl_xor(mx, 16));
    mx = fmaxf(mx, __shfl_xor(mx, 32));
    float sum = 0.f;
    #pragma unroll
    for (int i = 0; i < 16; ++i) { p[i] = __expf(p[i] - mx); sum += p[i]; }
    sum += __shfl_xor(sum, 16);
    sum += __shfl_xor(sum, 32);
    const float inv = 1.0f / sum;
    #pragma unroll
    for (int t = 0; t < 4; ++t) {
      u16x4 pk;
      #pragma unroll
      for (int r = 0; r < 4; ++r) pk[r] = f2bf(p[t * 4 + r] * inv);
      *(u16x4*)(Pw + c * 72 + t * 16 + g * 4) = pk;  // P[q-local=c][k]
    }

    // PV: A = P (wave-private), B = Vt[d][tok]
    f32x4 o0 = z, o1 = z;
    #pragma unroll
    for (int ks = 0; ks < 2; ++ks) {
      const bf16x8 ap = *(const bf16x8*)(Pw + c * 72 + ks * 32 + g * 8);
      const bf16x8 v0 = *(const bf16x8*)(Vt + (h * 32 + c) * 72 + ks * 32 + g * 8);
      const bf16x8 v1 = *(const bf16x8*)(Vt + (h * 32 + 16 + c) * 72 + ks * 32 + g * 8);
      o0 = MFMA(ap, v0, o0);
      o1 = MFMA(ap, v1, o1);
    }
    #pragma unroll
    for (int r = 0; r < 4; ++r) {
      Pw[(4 * g + r) * 72 + c]      = f2bf(o0[r]);
      Pw[(4 * g + r) * 72 + 16 + c] = f2bf(o1[r]);
    }
    uint4 ov = *(const uint4*)(Pw + c * 72 + g * 8);
    if (qvalid)
      *(uint4*)(qkv + (tokbase + q) * 576 + h * 32 + g * 8) = ov;
  }
}

// ---------------- K3: output projection, 128 rows/block ----------------
// grid 1568, 512 threads. Wave w8 owns rows w8*16..15, all 192 out cols.
__global__ __launch_bounds__(512, 4)
void out_gemm(const unsigned short* __restrict__ qkv, const unsigned short* __restrict__ WoT,
              const float* __restrict__ bo, float* __restrict__ out) {
  __shared__ __align__(16) unsigned short Ws[192 * 200];  // 76.8 KB, padded

  const int tid = threadIdx.x, w8 = tid >> 6, lane = tid & 63;
  const int g = lane >> 4, c = lane & 15;
  const size_t bm = (size_t)blockIdx.x * 128;
  const f32x4 z = {0.f, 0.f, 0.f, 0.f};

  #pragma unroll
  for (int jj = 0; jj < 9; ++jj) {  // 192 rows x 24 chunks of 16B
    int j = tid + jj * 512;
    *(uint4*)(&Ws[(j / 24) * 200 + (j % 24) * 8]) = *(const uint4*)(WoT + (j / 24) * 192 + (j % 24) * 8);
  }
  __syncthreads();

  bf16x8 af[6];
  #pragma unroll
  for (int ks = 0; ks < 6; ++ks)
    af[ks] = *(const bf16x8*)(qkv + (bm + w8 * 16 + c) * 576 + ks * 32 + g * 8);

  #pragma unroll
  for (int nf = 0; nf < 12; ++nf) {
    const int col = nf * 16 + c;
    const unsigned short* bp = Ws + col * 200;
    f32x4 acc = z;
    #pragma unroll
    for (int ks = 0; ks < 6; ++ks)
      acc = MFMA(af[ks], *(const bf16x8*)(bp + ks * 32 + g * 8), acc);
    const float bb = bo[col];
    #pragma unroll
    for (int r = 0; r < 4; ++r)
      out[(bm + w8 * 16 + 4 * g + r) * 192 + col] = acc[r] + bb;
  }
}

extern "C" void kernel_launch(void* const* d_in, const int* in_sizes, int n_in,
                              void* d_out, int out_size, void* d_ws, size_t ws_size,
                              hipStream_t stream) {
  (void)in_sizes; (void)n_in; (void)out_size; (void)ws_size;
  const float* X    = (const float*)d_in[0];
  const float* Wqkv = (const float*)d_in[1];
  const float* bqkv = (const float*)d_in[2];
  const float* Wo   = (const float*)d_in[3];
  const float* bo   = (const float*)d_in[4];
  const float* btab = (const float*)d_in[5];

  unsigned short* WqkvT = (unsigned short*)d_ws;   // 576*192 bf16
  unsigned short* WoT   = WqkvT + 576 * 192;       // 192*192 bf16
  unsigned short* qkv   = WoT + 192 * 192;         // 200704*576 bf16 (231 MB)

  wprep<<<432, 256, 0, stream>>>(Wqkv, Wo, WqkvT, WoT);
  qkv_gemm<<<1568, 512, 0, stream>>>(X, WqkvT, bqkv, qkv);
  attn_win<<<4096, 512, 0, stream>>>(qkv, btab);
  out_gemm<<<1568, 512, 0, stream>>>(qkv, WoT, bo, (float*)d_out);
}